// Round 7
// baseline (2206.537 us; speedup 1.0000x reference)
//
#include <hip/hip_runtime.h>
#include <hip/hip_bf16.h>
#include <stdint.h>

// SJ_SNN: bit-exact replica of the golden (jax on CPU -> XLA/Eigen fp32):
// per output element the contraction is a SINGLE accumulator, ascending k,
// true FMA. Verified PASS r6 (absmax 0.00390625 = golden bf16 floor).
// r7 perf changes (all order-preserving):
//  - GEMM 8x8 thread tile (was 8x4): 2x FMA per LDS byte.
//  - scans: chunk-level load prefetch + 64-thread blocks (all CUs engaged).
//  - sparse: LDS spike-list extraction, then batched loads (4 in flight);
//    add chain stays single-accumulator ascending.

__global__ void k_zero(unsigned int* __restrict__ p, int n){
  int i = blockIdx.x * 256 + threadIdx.x;
  if (i < n) p[i] = 0u;
}

// out[C][R] = in[R][C]  (exact fp32 copy)
__global__ void k_transpose(const float* __restrict__ in, float* __restrict__ out, int R, int C){
  __shared__ float tile[32][33];
  int bx = blockIdx.x * 32, by = blockIdx.y * 32;
  int tx = threadIdx.x, ty = threadIdx.y;
  for (int i = ty; i < 32; i += 8)
    tile[i][tx] = in[(size_t)(by + i) * C + bx + tx];
  __syncthreads();
  for (int i = ty; i < 32; i += 8)
    out[(size_t)(bx + i) * R + by + tx] = tile[tx][i];
}

// Layer-0 GEMM, Eigen order: C[m][e] = (single ascending FMA chain over
// k=0..511 of x[m][k]*W0[e][k]) + bias[e].  128x128 tile, 8x8/thread.
__global__ __launch_bounds__(256) void k_gemm_np(const float* __restrict__ A,
    const float* __restrict__ Bw, const float* __restrict__ bias,
    float* __restrict__ C, int M){
  (void)M;
  __shared__ float As[32][129];
  __shared__ float Bs[32][129];
  int bm = blockIdx.x * 128;
  int bn = blockIdx.y * 128;
  int tid = threadIdx.x;
  int kk = tid & 31, g = tid >> 5;   // staging: 8 groups x 32 k
  int tm = tid >> 4, tn = tid & 15;  // compute: 8 rows x 8 cols per thread
  float acc[8][8];
#pragma unroll
  for (int ii = 0; ii < 8; ++ii)
#pragma unroll
    for (int jj = 0; jj < 8; ++jj) acc[ii][jj] = 0.f;

  for (int k0 = 0; k0 < 512; k0 += 32){
#pragma unroll
    for (int rr = 0; rr < 16; ++rr)
      As[kk][g + rr * 8] = A[(size_t)(bm + g + rr * 8) * 512 + k0 + kk];
#pragma unroll
    for (int rr = 0; rr < 16; ++rr)
      Bs[kk][g + rr * 8] = Bw[(size_t)(bn + g + rr * 8) * 512 + k0 + kk];
    __syncthreads();
#pragma unroll
    for (int k = 0; k < 32; ++k){      // ascending k, single FMA chain/output
      float a[8], b[8];
#pragma unroll
      for (int ii = 0; ii < 8; ++ii) a[ii] = As[k][tm * 8 + ii];
#pragma unroll
      for (int jj = 0; jj < 8; ++jj) b[jj] = Bs[k][tn * 8 + jj];
#pragma unroll
      for (int ii = 0; ii < 8; ++ii)
#pragma unroll
        for (int jj = 0; jj < 8; ++jj)
          acc[ii][jj] = __fmaf_rn(a[ii], b[jj], acc[ii][jj]);
    }
    __syncthreads();
  }
#pragma unroll
  for (int ii = 0; ii < 8; ++ii){
    size_t m = (size_t)(bm + tm * 8 + ii);
#pragma unroll
    for (int jj = 0; jj < 8; ++jj){
      int e = bn + tn * 8 + jj;
      C[m * 1024 + e] = __fadd_rn(acc[ii][jj], bias[e]);
    }
  }
}

// BN stats: per (chunk, channel), SEQUENTIAL in-order over 256 samples.
__global__ __launch_bounds__(256) void k_stats_np(const float* __restrict__ A,
    float* __restrict__ mu, float* __restrict__ var, int Dch, int c0){
  int cl = blockIdx.x;
  int ch = blockIdx.y * 256 + threadIdx.x;
  const float* base = A + (size_t)cl * 256 * Dch + ch;
  float acc = 0.f;
  for (int s = 0; s < 256; ++s)
    acc = __fadd_rn(acc, base[(size_t)s * Dch]);
  float m = __fmul_rn(acc, 1.f / 256.f);   // /256 exact (pow2)
  float vacc = 0.f;
  for (int s = 0; s < 256; ++s){
    float d = __fsub_rn(base[(size_t)s * Dch], m);
    vacc = __fadd_rn(vacc, __fmul_rn(d, d));
  }
  int c = c0 + cl;
  mu[(size_t)c * Dch + ch]  = m;
  var[(size_t)c * Dch + ch] = __fmul_rn(vacc, 1.f / 256.f);
}

// fp32 BN + LIF scan (hidden layers): spike bitmasks, 64-thread blocks,
// software-pipelined chunk prefetch (8 independent loads in flight).
__global__ __launch_bounds__(64) void k_scan_spike_np(const float* __restrict__ A,
    const float* __restrict__ mu, const float* __restrict__ var,
    const float* __restrict__ g, const float* __restrict__ bt,
    float* __restrict__ vstate, unsigned long long* __restrict__ mask,
    int Dch, int c0, int nb){
  int ebn = Dch >> 6;
  int eb = blockIdx.x % ebn;
  int b  = blockIdx.x / ebn;
  int e  = (eb << 6) + threadIdx.x;
  float gg = g[e], bb = bt[e];
  float v = vstate[(size_t)b * Dch + e];
  float hbuf[8];
#pragma unroll
  for (int t = 0; t < 8; ++t)
    hbuf[t] = A[(size_t)(t * 32 + b) * Dch + e];
  for (int cl = 0; cl < nb; ++cl){
    int c = c0 + cl;
    float m  = mu[(size_t)c * Dch + e];
    float ve = __fadd_rn(var[(size_t)c * Dch + e], 1e-5f);
    float sq = (float)sqrt((double)ve);          // correctly-rounded fp32 sqrt
    float r  = (float)(1.0 / (double)sq);        // correctly-rounded fp32 div
    float hn[8];
    if (cl + 1 < nb){
#pragma unroll
      for (int t = 0; t < 8; ++t)
        hn[t] = A[(size_t)(((cl + 1) * 8 + t) * 32 + b) * Dch + e];
    } else {
#pragma unroll
      for (int t = 0; t < 8; ++t) hn[t] = 0.f;
    }
#pragma unroll
    for (int t = 0; t < 8; ++t){
      int sl = (cl * 8 + t) * 32 + b;
      float xn = __fadd_rn(__fmul_rn(__fmul_rn(gg, __fsub_rn(hbuf[t], m)), r), bb);
      v = __fadd_rn(v, __fmul_rn(__fsub_rn(xn, v), 0.5f));
      bool sp = (v >= 1.0f);                     // == (v-1>=0)
      unsigned long long bal = __ballot(sp);
      if (sp) v = 0.0f;
      if (threadIdx.x == 0) mask[(size_t)sl * 16 + eb] = bal;
    }
#pragma unroll
    for (int t = 0; t < 8; ++t) hbuf[t] = hn[t];
  }
  vstate[(size_t)b * Dch + e] = v;
}

// Sparse spike linear, Eigen order: thread 0 of each sample-slot extracts the
// ascending spike list into LDS; waves consume with 4 loads in flight.
// Single-accumulator ascending add chain preserved exactly.
__global__ __launch_bounds__(256) void k_sparse_np(const unsigned long long* __restrict__ mask,
    const float* __restrict__ WT, const float* __restrict__ bias,
    float* __restrict__ C, int Dout){
  int tid = threadIdx.x;
  int lane = tid & 63;
  int wid = tid >> 6;
  int wps = Dout >> 8;            // waves per sample: 4 (1024) or 2 (512)
  int chgrp = wid % wps;
  int sgrp  = wid / wps;
  int spb   = 4 / wps;            // samples per block
  int s = blockIdx.x * spb + sgrp;
  int ch = (chgrp << 8) + (lane << 2);
  __shared__ unsigned short list[2][1024];
  __shared__ int nlist[2];

  if (lane == 0 && chgrp == 0){
    const unsigned long long* mrow = mask + (size_t)s * 16;
    int n = 0;
    for (int w = 0; w < 16; ++w){
      unsigned long long msk = mrow[w];
      while (msk){
        int bit = __ffsll((unsigned long long)msk) - 1;
        msk &= msk - 1;
        list[sgrp][n++] = (unsigned short)(w * 64 + bit);
      }
    }
    nlist[sgrp] = n;
  }
  __syncthreads();
  int n = nlist[sgrp];
  const unsigned short* il = list[sgrp];
  float a0 = 0.f, a1 = 0.f, a2 = 0.f, a3 = 0.f;
  int i = 0;
  for (; i + 4 <= n; i += 4){
    int d0 = il[i], d1 = il[i + 1], d2 = il[i + 2], d3 = il[i + 3];
    float4 w0 = *(const float4*)(WT + (size_t)d0 * Dout + ch);
    float4 w1 = *(const float4*)(WT + (size_t)d1 * Dout + ch);
    float4 w2 = *(const float4*)(WT + (size_t)d2 * Dout + ch);
    float4 w3 = *(const float4*)(WT + (size_t)d3 * Dout + ch);
    a0 = __fadd_rn(a0, w0.x); a1 = __fadd_rn(a1, w0.y); a2 = __fadd_rn(a2, w0.z); a3 = __fadd_rn(a3, w0.w);
    a0 = __fadd_rn(a0, w1.x); a1 = __fadd_rn(a1, w1.y); a2 = __fadd_rn(a2, w1.z); a3 = __fadd_rn(a3, w1.w);
    a0 = __fadd_rn(a0, w2.x); a1 = __fadd_rn(a1, w2.y); a2 = __fadd_rn(a2, w2.z); a3 = __fadd_rn(a3, w2.w);
    a0 = __fadd_rn(a0, w3.x); a1 = __fadd_rn(a1, w3.y); a2 = __fadd_rn(a2, w3.z); a3 = __fadd_rn(a3, w3.w);
  }
  for (; i < n; ++i){
    int d = il[i];
    float4 wv = *(const float4*)(WT + (size_t)d * Dout + ch);
    a0 = __fadd_rn(a0, wv.x); a1 = __fadd_rn(a1, wv.y); a2 = __fadd_rn(a2, wv.z); a3 = __fadd_rn(a3, wv.w);
  }
  float4 bb = *(const float4*)(bias + ch);
  float4 o;
  o.x = __fadd_rn(a0, bb.x);
  o.y = __fadd_rn(a1, bb.y);
  o.z = __fadd_rn(a2, bb.z);
  o.w = __fadd_rn(a3, bb.w);
  *(float4*)(C + (size_t)s * Dout + ch) = o;
}

// Last layer: fp32 leaky integrator; sequential mean over 8 timesteps,
// /8 exact; float32 out. 64-thread blocks + chunk prefetch.
__global__ __launch_bounds__(64) void k_scan_last_np(const float* __restrict__ A,
    const float* __restrict__ mu, const float* __restrict__ var,
    const float* __restrict__ g, const float* __restrict__ bt,
    float* __restrict__ vstate, float* __restrict__ out, int c0, int nb){
  const int Dch = 512;
  int eb = blockIdx.x & 7;
  int b  = blockIdx.x >> 3;
  int e  = (eb << 6) + threadIdx.x;
  float gg = g[e], bb = bt[e];
  float v = vstate[(size_t)b * Dch + e];
  float hbuf[8];
#pragma unroll
  for (int t = 0; t < 8; ++t)
    hbuf[t] = A[(size_t)(t * 32 + b) * Dch + e];
  for (int cl = 0; cl < nb; ++cl){
    int c = c0 + cl;
    float m  = mu[(size_t)c * Dch + e];
    float ve = __fadd_rn(var[(size_t)c * Dch + e], 1e-5f);
    float sq = (float)sqrt((double)ve);
    float r  = (float)(1.0 / (double)sq);
    float hn[8];
    if (cl + 1 < nb){
#pragma unroll
      for (int t = 0; t < 8; ++t)
        hn[t] = A[(size_t)(((cl + 1) * 8 + t) * 32 + b) * Dch + e];
    } else {
#pragma unroll
      for (int t = 0; t < 8; ++t) hn[t] = 0.f;
    }
    float macc = 0.f;
#pragma unroll
    for (int t = 0; t < 8; ++t){
      float xn = __fadd_rn(__fmul_rn(__fmul_rn(gg, __fsub_rn(hbuf[t], m)), r), bb);
      v = __fadd_rn(v, __fmul_rn(__fsub_rn(xn, v), 0.5f));
      macc = __fadd_rn(macc, v);
    }
    out[((size_t)c * 32 + b) * 512 + e] = __fmul_rn(macc, 0.125f);
#pragma unroll
    for (int t = 0; t < 8; ++t) hbuf[t] = hn[t];
  }
  vstate[(size_t)b * Dch + e] = v;
}

static inline size_t al256(size_t x){ return (x + 255) & ~(size_t)255; }

extern "C" void kernel_launch(void* const* d_in, const int* in_sizes, int n_in,
                              void* d_out, int out_size, void* d_ws, size_t ws_size,
                              hipStream_t stream){
  (void)in_sizes; (void)n_in; (void)out_size;
  const float* x   = (const float*)d_in[0];
  const float* W0  = (const float*)d_in[1];
  const float* b0  = (const float*)d_in[2];
  const float* g0  = (const float*)d_in[3];
  const float* bt0 = (const float*)d_in[4];
  const float* W1  = (const float*)d_in[5];
  const float* b1  = (const float*)d_in[6];
  const float* g1  = (const float*)d_in[7];
  const float* bt1 = (const float*)d_in[8];
  const float* W2  = (const float*)d_in[9];
  const float* b2  = (const float*)d_in[10];
  const float* g2  = (const float*)d_in[11];
  const float* bt2 = (const float*)d_in[12];
  float* out = (float*)d_out;   // reference output dtype: float32

  char* p = (char*)d_ws;
  auto carve = [&](size_t bytes)->char*{ char* q = p; p += al256(bytes); return q; };
  float* W1T  = (float*)carve((size_t)1024 * 1024 * 4);   // [d=1024][e=1024]
  float* W2T  = (float*)carve((size_t)1024 * 512 * 4);    // [d=1024][e=512]
  float* mu0  = (float*)carve((size_t)128 * 1024 * 4);
  float* var0 = (float*)carve((size_t)128 * 1024 * 4);
  float* mu1  = (float*)carve((size_t)128 * 1024 * 4);
  float* var1 = (float*)carve((size_t)128 * 1024 * 4);
  float* mu2  = (float*)carve((size_t)128 * 512 * 4);
  float* var2 = (float*)carve((size_t)128 * 512 * 4);
  float* v0   = (float*)carve((size_t)32 * 1024 * 4);
  float* v1   = (float*)carve((size_t)32 * 1024 * 4);
  float* v2   = (float*)carve((size_t)32 * 512 * 4);
  size_t fixed_used = (size_t)(p - (char*)d_ws);

  auto need = [&](int nb)->size_t{
    return al256((size_t)nb * 256 * 1024 * 4)        // fp32 activation buffer
         + 2 * al256((size_t)nb * 256 * 16 * 8);     // mask0, mask1
  };
  int NB = 128;
  while (NB > 1 && fixed_used + need(NB) > ws_size) NB >>= 1;
  if (fixed_used + need(NB) > ws_size) return;

  float*              a_buf = (float*)carve((size_t)NB * 256 * 1024 * 4);
  unsigned long long* mask0 = (unsigned long long*)carve((size_t)NB * 256 * 16 * 8);
  unsigned long long* mask1 = (unsigned long long*)carve((size_t)NB * 256 * 16 * 8);

  // zero v-states (carved contiguously: 32*(1024+1024+512) floats)
  {
    int nz = 32 * (1024 + 1024 + 512);
    k_zero<<<dim3((nz + 255) / 256), dim3(256), 0, stream>>>((unsigned int*)v0, nz);
  }
  k_transpose<<<dim3(32, 32), dim3(32, 8), 0, stream>>>(W1, W1T, 1024, 1024);
  k_transpose<<<dim3(32, 16), dim3(32, 8), 0, stream>>>(W2, W2T, 512, 1024);

  int nblk = 128 / NB;
  for (int cb = 0; cb < nblk; ++cb){
    int c0 = cb * NB;
    int M = NB * 256;
    const float* xblk = x + (size_t)c0 * 256 * 512;

    // Layer 0 (Eigen-order FMA GEMM, 128x128 tiles)
    k_gemm_np<<<dim3(M / 128, 8), dim3(256), 0, stream>>>(xblk, W0, b0, a_buf, M);
    k_stats_np<<<dim3(NB, 4), dim3(256), 0, stream>>>(a_buf, mu0, var0, 1024, c0);
    k_scan_spike_np<<<dim3(32 * 16), dim3(64), 0, stream>>>(a_buf, mu0, var0, g0, bt0, v0, mask0, 1024, c0, NB);

    // Layer 1 (sparse, ascending single-chain, batched loads)
    k_sparse_np<<<dim3(M), dim3(256), 0, stream>>>(mask0, W1T, b1, a_buf, 1024);
    k_stats_np<<<dim3(NB, 4), dim3(256), 0, stream>>>(a_buf, mu1, var1, 1024, c0);
    k_scan_spike_np<<<dim3(32 * 16), dim3(64), 0, stream>>>(a_buf, mu1, var1, g1, bt1, v1, mask1, 1024, c0, NB);

    // Layer 2 (sparse) + integrator output
    k_sparse_np<<<dim3(M / 2), dim3(256), 0, stream>>>(mask1, W2T, b2, a_buf, 512);
    k_stats_np<<<dim3(NB, 2), dim3(256), 0, stream>>>(a_buf, mu2, var2, 512, c0);
    k_scan_last_np<<<dim3(32 * 8), dim3(64), 0, stream>>>(a_buf, mu2, var2, g2, bt2, v2, out, c0, NB);
  }
}

// Round 8
// 1296.097 us; speedup vs baseline: 1.7024x; 1.7024x over previous
//
#include <hip/hip_runtime.h>
#include <hip/hip_bf16.h>
#include <stdint.h>

// SJ_SNN: bit-exact replica of the golden (jax on CPU -> XLA/Eigen fp32):
// per output element the contraction is a SINGLE accumulator, ascending k,
// true FMA. PASS r6/r7 (absmax 0.00390625 = golden bf16 floor).
// r8 = best-of-both: r6 GEMM (8x4 tile, 96 VGPR, 2-way-max LDS conflicts)
// + r7 scans/sparse (−450 µs) + n-major GEMM grid for x-tile L2 reuse.
// r7 lesson: 8x8 tile => Bs[tn*8] 4-way bank conflicts (1.6e8) + 140 VGPR
// occupancy cliff => 2.4x slower GEMM. Don't re-try without XOR swizzle.

__global__ void k_zero(unsigned int* __restrict__ p, int n){
  int i = blockIdx.x * 256 + threadIdx.x;
  if (i < n) p[i] = 0u;
}

// out[C][R] = in[R][C]  (exact fp32 copy)
__global__ void k_transpose(const float* __restrict__ in, float* __restrict__ out, int R, int C){
  __shared__ float tile[32][33];
  int bx = blockIdx.x * 32, by = blockIdx.y * 32;
  int tx = threadIdx.x, ty = threadIdx.y;
  for (int i = ty; i < 32; i += 8)
    tile[i][tx] = in[(size_t)(by + i) * C + bx + tx];
  __syncthreads();
  for (int i = ty; i < 32; i += 8)
    out[(size_t)(bx + i) * R + by + tx] = tile[tx][i];
}

// Layer-0 GEMM, Eigen order: C[m][e] = (single ascending FMA chain over
// k=0..511 of x[m][k]*W0[e][k]) + bias[e].
// 128(m) x 64(n) block tile, 8x4 per thread. Grid: x = n-tile (fast) for L2
// reuse of the A(x) stream across co-resident blocks.
__global__ __launch_bounds__(256) void k_gemm_np(const float* __restrict__ A,
    const float* __restrict__ Bw, const float* __restrict__ bias,
    float* __restrict__ C, int M){
  (void)M;
  __shared__ float As[32][129];
  __shared__ float Bs[32][65];
  int bm = blockIdx.y * 128;
  int bn = blockIdx.x * 64;
  int tid = threadIdx.x;
  int kk = tid & 31, g = tid >> 5;   // staging
  int tm = tid >> 4, tn = tid & 15;  // compute: 8 rows x 4 cols per thread
  float acc[8][4];
#pragma unroll
  for (int ii = 0; ii < 8; ++ii)
#pragma unroll
    for (int jj = 0; jj < 4; ++jj) acc[ii][jj] = 0.f;

  for (int k0 = 0; k0 < 512; k0 += 32){
#pragma unroll
    for (int rr = 0; rr < 16; ++rr)
      As[kk][g + rr * 8] = A[(size_t)(bm + g + rr * 8) * 512 + k0 + kk];
#pragma unroll
    for (int rr = 0; rr < 8; ++rr)
      Bs[kk][g + rr * 8] = Bw[(size_t)(bn + g + rr * 8) * 512 + k0 + kk];
    __syncthreads();
#pragma unroll
    for (int k = 0; k < 32; ++k){      // ascending k, single FMA chain
      float a[8], b[4];
#pragma unroll
      for (int ii = 0; ii < 8; ++ii) a[ii] = As[k][tm * 8 + ii];
#pragma unroll
      for (int jj = 0; jj < 4; ++jj) b[jj] = Bs[k][tn * 4 + jj];
#pragma unroll
      for (int ii = 0; ii < 8; ++ii)
#pragma unroll
        for (int jj = 0; jj < 4; ++jj)
          acc[ii][jj] = __fmaf_rn(a[ii], b[jj], acc[ii][jj]);
    }
    __syncthreads();
  }
#pragma unroll
  for (int ii = 0; ii < 8; ++ii){
    size_t m = (size_t)(bm + tm * 8 + ii);
#pragma unroll
    for (int jj = 0; jj < 4; ++jj){
      int e = bn + tn * 4 + jj;
      C[m * 1024 + e] = __fadd_rn(acc[ii][jj], bias[e]);
    }
  }
}

// BN stats: per (chunk, channel), SEQUENTIAL in-order over 256 samples.
__global__ __launch_bounds__(256) void k_stats_np(const float* __restrict__ A,
    float* __restrict__ mu, float* __restrict__ var, int Dch, int c0){
  int cl = blockIdx.x;
  int ch = blockIdx.y * 256 + threadIdx.x;
  const float* base = A + (size_t)cl * 256 * Dch + ch;
  float acc = 0.f;
  for (int s = 0; s < 256; ++s)
    acc = __fadd_rn(acc, base[(size_t)s * Dch]);
  float m = __fmul_rn(acc, 1.f / 256.f);   // /256 exact (pow2)
  float vacc = 0.f;
  for (int s = 0; s < 256; ++s){
    float d = __fsub_rn(base[(size_t)s * Dch], m);
    vacc = __fadd_rn(vacc, __fmul_rn(d, d));
  }
  int c = c0 + cl;
  mu[(size_t)c * Dch + ch]  = m;
  var[(size_t)c * Dch + ch] = __fmul_rn(vacc, 1.f / 256.f);
}

// fp32 BN + LIF scan (hidden layers): spike bitmasks, 64-thread blocks,
// software-pipelined chunk prefetch (8 independent loads in flight).
__global__ __launch_bounds__(64) void k_scan_spike_np(const float* __restrict__ A,
    const float* __restrict__ mu, const float* __restrict__ var,
    const float* __restrict__ g, const float* __restrict__ bt,
    float* __restrict__ vstate, unsigned long long* __restrict__ mask,
    int Dch, int c0, int nb){
  int ebn = Dch >> 6;
  int eb = blockIdx.x % ebn;
  int b  = blockIdx.x / ebn;
  int e  = (eb << 6) + threadIdx.x;
  float gg = g[e], bb = bt[e];
  float v = vstate[(size_t)b * Dch + e];
  float hbuf[8];
#pragma unroll
  for (int t = 0; t < 8; ++t)
    hbuf[t] = A[(size_t)(t * 32 + b) * Dch + e];
  for (int cl = 0; cl < nb; ++cl){
    int c = c0 + cl;
    float m  = mu[(size_t)c * Dch + e];
    float ve = __fadd_rn(var[(size_t)c * Dch + e], 1e-5f);
    float sq = (float)sqrt((double)ve);          // correctly-rounded fp32 sqrt
    float r  = (float)(1.0 / (double)sq);        // correctly-rounded fp32 div
    float hn[8];
    if (cl + 1 < nb){
#pragma unroll
      for (int t = 0; t < 8; ++t)
        hn[t] = A[(size_t)(((cl + 1) * 8 + t) * 32 + b) * Dch + e];
    } else {
#pragma unroll
      for (int t = 0; t < 8; ++t) hn[t] = 0.f;
    }
#pragma unroll
    for (int t = 0; t < 8; ++t){
      int sl = (cl * 8 + t) * 32 + b;
      float xn = __fadd_rn(__fmul_rn(__fmul_rn(gg, __fsub_rn(hbuf[t], m)), r), bb);
      v = __fadd_rn(v, __fmul_rn(__fsub_rn(xn, v), 0.5f));
      bool sp = (v >= 1.0f);                     // == (v-1>=0)
      unsigned long long bal = __ballot(sp);
      if (sp) v = 0.0f;
      if (threadIdx.x == 0) mask[(size_t)sl * 16 + eb] = bal;
    }
#pragma unroll
    for (int t = 0; t < 8; ++t) hbuf[t] = hn[t];
  }
  vstate[(size_t)b * Dch + e] = v;
}

// Sparse spike linear, Eigen order: thread 0 of each sample-slot extracts the
// ascending spike list into LDS; waves consume with 4 loads in flight.
// Single-accumulator ascending add chain preserved exactly.
__global__ __launch_bounds__(256) void k_sparse_np(const unsigned long long* __restrict__ mask,
    const float* __restrict__ WT, const float* __restrict__ bias,
    float* __restrict__ C, int Dout){
  int tid = threadIdx.x;
  int lane = tid & 63;
  int wid = tid >> 6;
  int wps = Dout >> 8;            // waves per sample: 4 (1024) or 2 (512)
  int chgrp = wid % wps;
  int sgrp  = wid / wps;
  int spb   = 4 / wps;            // samples per block
  int s = blockIdx.x * spb + sgrp;
  int ch = (chgrp << 8) + (lane << 2);
  __shared__ unsigned short list[2][1024];
  __shared__ int nlist[2];

  if (lane == 0 && chgrp == 0){
    const unsigned long long* mrow = mask + (size_t)s * 16;
    int n = 0;
    for (int w = 0; w < 16; ++w){
      unsigned long long msk = mrow[w];
      while (msk){
        int bit = __ffsll((unsigned long long)msk) - 1;
        msk &= msk - 1;
        list[sgrp][n++] = (unsigned short)(w * 64 + bit);
      }
    }
    nlist[sgrp] = n;
  }
  __syncthreads();
  int n = nlist[sgrp];
  const unsigned short* il = list[sgrp];
  float a0 = 0.f, a1 = 0.f, a2 = 0.f, a3 = 0.f;
  int i = 0;
  for (; i + 4 <= n; i += 4){
    int d0 = il[i], d1 = il[i + 1], d2 = il[i + 2], d3 = il[i + 3];
    float4 w0 = *(const float4*)(WT + (size_t)d0 * Dout + ch);
    float4 w1 = *(const float4*)(WT + (size_t)d1 * Dout + ch);
    float4 w2 = *(const float4*)(WT + (size_t)d2 * Dout + ch);
    float4 w3 = *(const float4*)(WT + (size_t)d3 * Dout + ch);
    a0 = __fadd_rn(a0, w0.x); a1 = __fadd_rn(a1, w0.y); a2 = __fadd_rn(a2, w0.z); a3 = __fadd_rn(a3, w0.w);
    a0 = __fadd_rn(a0, w1.x); a1 = __fadd_rn(a1, w1.y); a2 = __fadd_rn(a2, w1.z); a3 = __fadd_rn(a3, w1.w);
    a0 = __fadd_rn(a0, w2.x); a1 = __fadd_rn(a1, w2.y); a2 = __fadd_rn(a2, w2.z); a3 = __fadd_rn(a3, w2.w);
    a0 = __fadd_rn(a0, w3.x); a1 = __fadd_rn(a1, w3.y); a2 = __fadd_rn(a2, w3.z); a3 = __fadd_rn(a3, w3.w);
  }
  for (; i < n; ++i){
    int d = il[i];
    float4 wv = *(const float4*)(WT + (size_t)d * Dout + ch);
    a0 = __fadd_rn(a0, wv.x); a1 = __fadd_rn(a1, wv.y); a2 = __fadd_rn(a2, wv.z); a3 = __fadd_rn(a3, wv.w);
  }
  float4 bb = *(const float4*)(bias + ch);
  float4 o;
  o.x = __fadd_rn(a0, bb.x);
  o.y = __fadd_rn(a1, bb.y);
  o.z = __fadd_rn(a2, bb.z);
  o.w = __fadd_rn(a3, bb.w);
  *(float4*)(C + (size_t)s * Dout + ch) = o;
}

// Last layer: fp32 leaky integrator; sequential mean over 8 timesteps,
// /8 exact; float32 out. 64-thread blocks + chunk prefetch.
__global__ __launch_bounds__(64) void k_scan_last_np(const float* __restrict__ A,
    const float* __restrict__ mu, const float* __restrict__ var,
    const float* __restrict__ g, const float* __restrict__ bt,
    float* __restrict__ vstate, float* __restrict__ out, int c0, int nb){
  const int Dch = 512;
  int eb = blockIdx.x & 7;
  int b  = blockIdx.x >> 3;
  int e  = (eb << 6) + threadIdx.x;
  float gg = g[e], bb = bt[e];
  float v = vstate[(size_t)b * Dch + e];
  float hbuf[8];
#pragma unroll
  for (int t = 0; t < 8; ++t)
    hbuf[t] = A[(size_t)(t * 32 + b) * Dch + e];
  for (int cl = 0; cl < nb; ++cl){
    int c = c0 + cl;
    float m  = mu[(size_t)c * Dch + e];
    float ve = __fadd_rn(var[(size_t)c * Dch + e], 1e-5f);
    float sq = (float)sqrt((double)ve);
    float r  = (float)(1.0 / (double)sq);
    float hn[8];
    if (cl + 1 < nb){
#pragma unroll
      for (int t = 0; t < 8; ++t)
        hn[t] = A[(size_t)(((cl + 1) * 8 + t) * 32 + b) * Dch + e];
    } else {
#pragma unroll
      for (int t = 0; t < 8; ++t) hn[t] = 0.f;
    }
    float macc = 0.f;
#pragma unroll
    for (int t = 0; t < 8; ++t){
      float xn = __fadd_rn(__fmul_rn(__fmul_rn(gg, __fsub_rn(hbuf[t], m)), r), bb);
      v = __fadd_rn(v, __fmul_rn(__fsub_rn(xn, v), 0.5f));
      macc = __fadd_rn(macc, v);
    }
    out[((size_t)c * 32 + b) * 512 + e] = __fmul_rn(macc, 0.125f);
#pragma unroll
    for (int t = 0; t < 8; ++t) hbuf[t] = hn[t];
  }
  vstate[(size_t)b * Dch + e] = v;
}

static inline size_t al256(size_t x){ return (x + 255) & ~(size_t)255; }

extern "C" void kernel_launch(void* const* d_in, const int* in_sizes, int n_in,
                              void* d_out, int out_size, void* d_ws, size_t ws_size,
                              hipStream_t stream){
  (void)in_sizes; (void)n_in; (void)out_size;
  const float* x   = (const float*)d_in[0];
  const float* W0  = (const float*)d_in[1];
  const float* b0  = (const float*)d_in[2];
  const float* g0  = (const float*)d_in[3];
  const float* bt0 = (const float*)d_in[4];
  const float* W1  = (const float*)d_in[5];
  const float* b1  = (const float*)d_in[6];
  const float* g1  = (const float*)d_in[7];
  const float* bt1 = (const float*)d_in[8];
  const float* W2  = (const float*)d_in[9];
  const float* b2  = (const float*)d_in[10];
  const float* g2  = (const float*)d_in[11];
  const float* bt2 = (const float*)d_in[12];
  float* out = (float*)d_out;   // reference output dtype: float32

  char* p = (char*)d_ws;
  auto carve = [&](size_t bytes)->char*{ char* q = p; p += al256(bytes); return q; };
  float* W1T  = (float*)carve((size_t)1024 * 1024 * 4);   // [d=1024][e=1024]
  float* W2T  = (float*)carve((size_t)1024 * 512 * 4);    // [d=1024][e=512]
  float* mu0  = (float*)carve((size_t)128 * 1024 * 4);
  float* var0 = (float*)carve((size_t)128 * 1024 * 4);
  float* mu1  = (float*)carve((size_t)128 * 1024 * 4);
  float* var1 = (float*)carve((size_t)128 * 1024 * 4);
  float* mu2  = (float*)carve((size_t)128 * 512 * 4);
  float* var2 = (float*)carve((size_t)128 * 512 * 4);
  float* v0   = (float*)carve((size_t)32 * 1024 * 4);
  float* v1   = (float*)carve((size_t)32 * 1024 * 4);
  float* v2   = (float*)carve((size_t)32 * 512 * 4);
  size_t fixed_used = (size_t)(p - (char*)d_ws);

  auto need = [&](int nb)->size_t{
    return al256((size_t)nb * 256 * 1024 * 4)        // fp32 activation buffer
         + 2 * al256((size_t)nb * 256 * 16 * 8);     // mask0, mask1
  };
  int NB = 128;
  while (NB > 1 && fixed_used + need(NB) > ws_size) NB >>= 1;
  if (fixed_used + need(NB) > ws_size) return;

  float*              a_buf = (float*)carve((size_t)NB * 256 * 1024 * 4);
  unsigned long long* mask0 = (unsigned long long*)carve((size_t)NB * 256 * 16 * 8);
  unsigned long long* mask1 = (unsigned long long*)carve((size_t)NB * 256 * 16 * 8);

  // zero v-states (carved contiguously: 32*(1024+1024+512) floats)
  {
    int nz = 32 * (1024 + 1024 + 512);
    k_zero<<<dim3((nz + 255) / 256), dim3(256), 0, stream>>>((unsigned int*)v0, nz);
  }
  k_transpose<<<dim3(32, 32), dim3(32, 8), 0, stream>>>(W1, W1T, 1024, 1024);
  k_transpose<<<dim3(32, 16), dim3(32, 8), 0, stream>>>(W2, W2T, 512, 1024);

  int nblk = 128 / NB;
  for (int cb = 0; cb < nblk; ++cb){
    int c0 = cb * NB;
    int M = NB * 256;
    const float* xblk = x + (size_t)c0 * 256 * 512;

    // Layer 0 (Eigen-order FMA GEMM; n-tile-major grid for x L2 reuse)
    k_gemm_np<<<dim3(16, M / 128), dim3(256), 0, stream>>>(xblk, W0, b0, a_buf, M);
    k_stats_np<<<dim3(NB, 4), dim3(256), 0, stream>>>(a_buf, mu0, var0, 1024, c0);
    k_scan_spike_np<<<dim3(32 * 16), dim3(64), 0, stream>>>(a_buf, mu0, var0, g0, bt0, v0, mask0, 1024, c0, NB);

    // Layer 1 (sparse, ascending single-chain, batched loads)
    k_sparse_np<<<dim3(M), dim3(256), 0, stream>>>(mask0, W1T, b1, a_buf, 1024);
    k_stats_np<<<dim3(NB, 4), dim3(256), 0, stream>>>(a_buf, mu1, var1, 1024, c0);
    k_scan_spike_np<<<dim3(32 * 16), dim3(64), 0, stream>>>(a_buf, mu1, var1, g1, bt1, v1, mask1, 1024, c0, NB);

    // Layer 2 (sparse) + integrator output
    k_sparse_np<<<dim3(M / 2), dim3(256), 0, stream>>>(mask1, W2T, b2, a_buf, 512);
    k_stats_np<<<dim3(NB, 2), dim3(256), 0, stream>>>(a_buf, mu2, var2, 512, c0);
    k_scan_last_np<<<dim3(32 * 8), dim3(64), 0, stream>>>(a_buf, mu2, var2, g2, bt2, v2, out, c0, NB);
  }
}